// Round 8
// baseline (1889.094 us; speedup 1.0000x reference)
//
#include <hip/hip_runtime.h>
#include <hip/hip_bf16.h>
#include <cstdint>
#include <cstddef>

#define NN 100000      // nodes
#define NE 1600000     // edges
#define HH 128         // hidden dim
#define NG 256         // graphs

#define NB 196         // buckets (512 nodes each; 196*512 = 100352 >= NN)
#define BSH 9          // bucket shift
#define BMSK 511
#define CHUNK 16384    // edges per binning block
#define NBLK 98        // ceil(NE / CHUNK)

#define EPB ((NE + 97) / 98)      // edges per edgepool block (x-dim 98)
#define NPB ((NN + 97) / 98)      // nodes per edgepool block (self terms)

typedef __bf16 bf16x8 __attribute__((ext_vector_type(8)));
typedef float floatx4 __attribute__((ext_vector_type(4)));

__device__ __forceinline__ uint32_t f2b(float f) {
  union { float f; uint32_t u; } v; v.f = f;
  uint32_t u = v.u;
  return (u + 0x7FFFu + ((u >> 16) & 1u)) >> 16;   // RNE to bf16 (raw 16 bits)
}
__device__ __forceinline__ float b2f(uint32_t h) {
  union { uint32_t u; float f; } v; v.u = h << 16;
  return v.f;
}
__device__ __forceinline__ void addrow(float* a, uint4 v) {
  a[0] += b2f(v.x & 0xFFFFu); a[1] += b2f(v.x >> 16);
  a[2] += b2f(v.y & 0xFFFFu); a[3] += b2f(v.y >> 16);
  a[4] += b2f(v.z & 0xFFFFu); a[5] += b2f(v.z >> 16);
  a[6] += b2f(v.w & 0xFFFFu); a[7] += b2f(v.w >> 16);
}

// ================= CSR build: src-bucket sort, then dst-bucket counting sort =================

__global__ __launch_bounds__(256) void k_cntA(const int* __restrict__ src,
                                              int* __restrict__ blkcnt) {
  __shared__ int h[NB];
  int t = threadIdx.x;
  if (t < NB) h[t] = 0;
  __syncthreads();
  int base = blockIdx.x * CHUNK, end = min(base + CHUNK, NE);
  for (int i = base + t; i < end; i += 256) atomicAdd(&h[src[i] >> BSH], 1);
  __syncthreads();
  if (t < NB) blkcnt[blockIdx.x * NB + t] = h[t];
}

__global__ __launch_bounds__(256) void k_cntB(const uint2* __restrict__ pairs,
                                              int* __restrict__ blkcnt) {
  __shared__ int h[NB];
  int t = threadIdx.x;
  if (t < NB) h[t] = 0;
  __syncthreads();
  int base = blockIdx.x * CHUNK, end = min(base + CHUNK, NE);
  for (int i = base + t; i < end; i += 256) atomicAdd(&h[pairs[i].y >> BSH], 1);
  __syncthreads();
  if (t < NB) blkcnt[blockIdx.x * NB + t] = h[t];
}

__global__ __launch_bounds__(64) void k_colscan(const int* __restrict__ blkcnt,
                                                int* __restrict__ poff,
                                                int* __restrict__ colsum) {
  int b = blockIdx.x, t = threadIdx.x;
  int carry = 0;
  for (int base = 0; base < NBLK; base += 64) {
    int r = base + t;
    int x = (r < NBLK) ? blkcnt[r * NB + b] : 0;
    int v = x;
    for (int d = 1; d < 64; d <<= 1) { int u = __shfl_up(v, d); if (t >= d) v += u; }
    if (r < NBLK) poff[r * NB + b] = carry + v - x;
    carry += __shfl(v, 63);
  }
  if (t == 0) colsum[b] = carry;
}

__global__ void k_gscan(const int* __restrict__ colsum, int* __restrict__ gbase,
                        int* __restrict__ off, int set_off) {
  __shared__ int s[256];
  int t = threadIdx.x;
  int x = (t < NB) ? colsum[t] : 0;
  s[t] = x; __syncthreads();
  for (int d = 1; d < 256; d <<= 1) {
    int v = (t >= d) ? s[t - d] : 0;
    __syncthreads();
    s[t] += v;
    __syncthreads();
  }
  if (t < NB) gbase[t] = s[t] - x;
  if (t == 0) { gbase[NB] = NE; if (set_off) off[NN] = NE; }
}

__global__ __launch_bounds__(256) void k_placeA(const int* __restrict__ src,
                                                const int* __restrict__ dst,
                                                const int* __restrict__ poff,
                                                const int* __restrict__ gbase,
                                                uint2* __restrict__ pairs) {
  __shared__ int cur[NB];
  int t = threadIdx.x;
  if (t < NB) cur[t] = poff[blockIdx.x * NB + t] + gbase[t];
  __syncthreads();
  int base = blockIdx.x * CHUNK, end = min(base + CHUNK, NE);
  for (int i = base + t; i < end; i += 256) {
    int s = src[i], d = dst[i];
    int p = atomicAdd(&cur[s >> BSH], 1);
    pairs[p] = make_uint2((unsigned)s, (unsigned)d);
  }
}

__global__ __launch_bounds__(256) void k_placeB(const uint2* __restrict__ pairs,
                                                const int* __restrict__ poff,
                                                const int* __restrict__ gbase,
                                                uint32_t* __restrict__ outb) {
  __shared__ int cur[NB];
  int t = threadIdx.x;
  if (t < NB) cur[t] = poff[blockIdx.x * NB + t] + gbase[t];
  __syncthreads();
  int base = blockIdx.x * CHUNK, end = min(base + CHUNK, NE);
  for (int i = base + t; i < end; i += 256) {
    uint2 v = pairs[i];
    int p = atomicAdd(&cur[v.y >> BSH], 1);
    outb[p] = v.x | ((v.y & (unsigned)BMSK) << 17);
  }
}

__global__ __launch_bounds__(256) void k_bucket_sort(
    const uint32_t* __restrict__ pairbuf, const int* __restrict__ gbase,
    int* __restrict__ off, float* __restrict__ inv, int* __restrict__ csrs)
{
  __shared__ int cnt[512];
  __shared__ int loff[512];
  __shared__ int psum[256];
  int b = blockIdx.x;
  int tid = threadIdx.x;
  cnt[tid] = 0; cnt[tid + 256] = 0;
  __syncthreads();
  int s0 = gbase[b], s1 = gbase[b + 1];
  for (int i = s0 + tid; i < s1; i += 256)
    atomicAdd(&cnt[pairbuf[i] >> 17], 1);
  __syncthreads();
  int a0 = cnt[2 * tid], a1 = cnt[2 * tid + 1];
  int s = a0 + a1;
  psum[tid] = s;
  __syncthreads();
  for (int d = 1; d < 256; d <<= 1) {
    int v = (tid >= d) ? psum[tid - d] : 0;
    __syncthreads();
    psum[tid] += v;
    __syncthreads();
  }
  int excl = psum[tid] - s;
  loff[2 * tid] = excl;
  loff[2 * tid + 1] = excl + a0;
  __syncthreads();
#pragma unroll
  for (int k = 0; k < 2; ++k) {
    int i = tid + k * 256;
    int node = b * 512 + i;
    if (node < NN) {
      off[node] = s0 + loff[i];
      inv[node] = rsqrtf((float)cnt[i] + 1.0f);
    }
  }
  __syncthreads();
  cnt[tid] = loff[tid]; cnt[tid + 256] = loff[tid + 256];
  __syncthreads();
  for (int i = s0 + tid; i < s1; i += 256) {
    uint32_t v = pairbuf[i];
    int p = atomicAdd(&cnt[v >> 17], 1);
    csrs[s0 + p] = (int)(v & 0x1FFFFu);
  }
}

// ================= degree sort (64 bins, descending for LPT scheduling) =================
__global__ __launch_bounds__(256) void k_deghist(const int* __restrict__ off,
                                                 int* __restrict__ dhist) {
  __shared__ int h[64];
  int t = threadIdx.x;
  if (t < 64) h[t] = 0;
  __syncthreads();
  int i = blockIdx.x * 256 + t;
  if (i < NN) { int d = off[i + 1] - off[i]; if (d > 63) d = 63; atomicAdd(&h[d], 1); }
  __syncthreads();
  if (t < 64 && h[t]) atomicAdd(&dhist[t], h[t]);
}

__global__ void k_dscan(const int* __restrict__ dhist, int* __restrict__ dcur) {
  int t = threadIdx.x;             // 64 threads; descending order (LPT)
  int x = dhist[63 - t];
  int v = x;
  for (int d = 1; d < 64; d <<= 1) { int u = __shfl_up(v, d); if (t >= d) v += u; }
  dcur[63 - t] = v - x;
}

__global__ __launch_bounds__(256) void k_dplace(const int* __restrict__ off,
                                                int* __restrict__ dcur,
                                                int* __restrict__ order) {
  __shared__ int h[64], base[64];
  int t = threadIdx.x;
  if (t < 64) h[t] = 0;
  __syncthreads();
  int i = blockIdx.x * 256 + t;
  int d = 0, ld = 0;
  if (i < NN) { d = off[i + 1] - off[i]; if (d > 63) d = 63; ld = atomicAdd(&h[d], 1); }
  __syncthreads();
  if (t < 64) base[t] = h[t] ? atomicAdd(&dcur[t], h[t]) : 0;
  __syncthreads();
  if (i < NN) order[base[d] + ld] = i;
}

// ================= edge prep for fused last layer: esg = src | batch[dst]<<17, ew = inv_s*inv_d =================
__global__ __launch_bounds__(256) void k_prep_edges(const uint2* __restrict__ pairs,
                                                    const float* __restrict__ inv,
                                                    const int* __restrict__ batch,
                                                    uint32_t* __restrict__ esg,
                                                    float* __restrict__ ew) {
  int i = blockIdx.x * 256 + threadIdx.x;
  if (i >= NE) return;
  uint2 p = pairs[i];
  esg[i] = p.x | ((uint32_t)batch[p.y] << 17);
  ew[i] = inv[p.x] * inv[p.y];
}

// ================= GEMM: Out[M,128] = bf16( scale[r] * (A[M,128] @ W + bias) ) =================
__global__ __launch_bounds__(256) void k_gemm(
    const uint16_t* __restrict__ A16, const float* __restrict__ A32,
    const float* __restrict__ W, const float* __restrict__ bias,
    const float* __restrict__ scale,      // nullptr or per-row scale (inv)
    uint16_t* __restrict__ Out, int M, int do_relu)
{
  __shared__ uint16_t Wt[128][136];
  const int tid = threadIdx.x;

  for (int it = 0; it < 16; ++it) {
    int idx = tid + it * 256;
    int n = idx & 127;
    int k0 = (idx >> 7) * 4;
    uint2 wv;
    wv.x = f2b(W[(k0 + 0) * 128 + n]) | (f2b(W[(k0 + 1) * 128 + n]) << 16);
    wv.y = f2b(W[(k0 + 2) * 128 + n]) | (f2b(W[(k0 + 3) * 128 + n]) << 16);
    *(uint2*)&Wt[n][k0] = wv;
  }
  __syncthreads();

  const int lane = tid & 63;
  const int wave = tid >> 6;
  const int lrow = lane & 15;
  const int lk = (lane >> 4) * 8;
  const int row0 = blockIdx.x * 128 + wave * 32;

  floatx4 acc[2][8];
#pragma unroll
  for (int t = 0; t < 2; ++t)
#pragma unroll
    for (int n = 0; n < 8; ++n)
      acc[t][n] = (floatx4){0.f, 0.f, 0.f, 0.f};

#pragma unroll
  for (int ks = 0; ks < 4; ++ks) {
    bf16x8 a[2];
#pragma unroll
    for (int t = 0; t < 2; ++t) {
      int r = row0 + t * 16 + lrow;
      uint4 tmp = {0u, 0u, 0u, 0u};
      if (r < M) {
        if (A32) {
          float4 f0 = *(const float4*)(A32 + (size_t)r * HH + ks * 32 + lk);
          float4 f1 = *(const float4*)(A32 + (size_t)r * HH + ks * 32 + lk + 4);
          tmp.x = f2b(f0.x) | (f2b(f0.y) << 16);
          tmp.y = f2b(f0.z) | (f2b(f0.w) << 16);
          tmp.z = f2b(f1.x) | (f2b(f1.y) << 16);
          tmp.w = f2b(f1.z) | (f2b(f1.w) << 16);
        } else {
          tmp = *(const uint4*)(A16 + (size_t)r * HH + ks * 32 + lk);
        }
      }
      a[t] = __builtin_bit_cast(bf16x8, tmp);
    }
#pragma unroll
    for (int n = 0; n < 8; ++n) {
      bf16x8 b = __builtin_bit_cast(bf16x8, *(const uint4*)&Wt[n * 16 + lrow][ks * 32 + lk]);
      acc[0][n] = __builtin_amdgcn_mfma_f32_16x16x32_bf16(a[0], b, acc[0][n], 0, 0, 0);
      acc[1][n] = __builtin_amdgcn_mfma_f32_16x16x32_bf16(a[1], b, acc[1][n], 0, 0, 0);
    }
  }

  float bc[8];
#pragma unroll
  for (int n = 0; n < 8; ++n) bc[n] = bias[n * 16 + lrow];

  const int rbase = (lane >> 4) * 4;
#pragma unroll
  for (int t = 0; t < 2; ++t) {
#pragma unroll
    for (int r = 0; r < 4; ++r) {
      int row = row0 + t * 16 + rbase + r;
      if (row < M) {
        float sc = scale ? scale[row] : 1.0f;
#pragma unroll
        for (int n = 0; n < 8; ++n) {
          float v = acc[t][n][r] + bc[n];
          if (do_relu) v = fmaxf(v, 0.f);
          v *= sc;
          Out[(size_t)row * HH + n * 16 + lrow] = (uint16_t)f2b(v);
        }
      }
    }
  }
}

// ================= aggregation: pre-scaled rows, pure gather-sum, unroll-4 =================
__global__ __launch_bounds__(256) void k_agg(
    const uint16_t* __restrict__ hw2, const int* __restrict__ off,
    const int* __restrict__ csrs, const float* __restrict__ inv,
    const int* __restrict__ order,
    uint16_t* __restrict__ hout, int do_relu)
{
  int slot = blockIdx.x * 16 + (threadIdx.x >> 4);
  if (slot >= NN) return;
  int node = order[slot];
  int c = (threadIdx.x & 15) * 8;   // 8 channels = 16 B per lane

  uint4 sv = *(const uint4*)(hw2 + (size_t)node * HH + c);
  float a[8] = {0.f, 0.f, 0.f, 0.f, 0.f, 0.f, 0.f, 0.f};
  addrow(a, sv);                    // self term (already inv[node]-scaled)

  int e0 = off[node], e1 = off[node + 1];
  int e = e0;
  for (; e + 4 <= e1; e += 4) {
    int s0 = csrs[e + 0], s1 = csrs[e + 1], s2 = csrs[e + 2], s3 = csrs[e + 3];
    uint4 v0 = *(const uint4*)(hw2 + (size_t)s0 * HH + c);
    uint4 v1 = *(const uint4*)(hw2 + (size_t)s1 * HH + c);
    uint4 v2 = *(const uint4*)(hw2 + (size_t)s2 * HH + c);
    uint4 v3 = *(const uint4*)(hw2 + (size_t)s3 * HH + c);
    addrow(a, v0); addrow(a, v1); addrow(a, v2); addrow(a, v3);
  }
  for (; e < e1; ++e) {
    int s = csrs[e];
    uint4 v = *(const uint4*)(hw2 + (size_t)s * HH + c);
    addrow(a, v);
  }
  float invd = inv[node];
#pragma unroll
  for (int j = 0; j < 8; ++j) {
    a[j] *= invd;
    if (do_relu) a[j] = fmaxf(a[j], 0.f);
  }
  uint4 o;
  o.x = f2b(a[0]) | (f2b(a[1]) << 16);
  o.y = f2b(a[2]) | (f2b(a[3]) << 16);
  o.z = f2b(a[4]) | (f2b(a[5]) << 16);
  o.w = f2b(a[6]) | (f2b(a[7]) << 16);
  *(uint4*)(hout + (size_t)node * HH + c) = o;
}

// ================= fused last layer: q[g] = sum_e w_e*h2[src_e] + sum_i inv_i^2*h2[i]; S[g] likewise =================
// grid (98, 4): x = edge/node chunk, y = 32-channel group. LDS tile 256x32 fp32.
__global__ __launch_bounds__(256) void k_edgepool(
    const uint16_t* __restrict__ h2, const uint32_t* __restrict__ esg,
    const float* __restrict__ ew, const float* __restrict__ inv,
    const int* __restrict__ batch,
    float* __restrict__ q, float* __restrict__ S)
{
  __shared__ float qlds[NG * 32];
  __shared__ float slds[NG];
  int tid = threadIdx.x;
  int y = blockIdx.y;
  for (int k = tid; k < NG * 32; k += 256) qlds[k] = 0.f;
  if (tid < NG) slds[tid] = 0.f;
  __syncthreads();

  int grp = tid >> 2;          // 64 edge groups
  int ln = tid & 3;            // 4 lanes -> 32 ch
  int cbase = y * 32 + ln * 8;
  int do_s = (y == 0 && ln == 0);

  // edges
  int e0 = blockIdx.x * EPB, e1 = min(e0 + EPB, NE);
  for (int e = e0 + grp; e < e1; e += 64) {
    uint32_t sg = esg[e];
    float w = ew[e];
    int s = sg & 0x1FFFF;
    int g = sg >> 17;
    uint4 v = *(const uint4*)(h2 + (size_t)s * HH + cbase);
    float* qr = &qlds[g * 32 + ln * 8];
    atomicAdd(&qr[0], w * b2f(v.x & 0xFFFFu));
    atomicAdd(&qr[1], w * b2f(v.x >> 16));
    atomicAdd(&qr[2], w * b2f(v.y & 0xFFFFu));
    atomicAdd(&qr[3], w * b2f(v.y >> 16));
    atomicAdd(&qr[4], w * b2f(v.z & 0xFFFFu));
    atomicAdd(&qr[5], w * b2f(v.z >> 16));
    atomicAdd(&qr[6], w * b2f(v.w & 0xFFFFu));
    atomicAdd(&qr[7], w * b2f(v.w >> 16));
    if (do_s) atomicAdd(&slds[g], w);
  }

  // self terms
  int n0 = blockIdx.x * NPB, n1 = min(n0 + NPB, NN);
  for (int i = n0 + grp; i < n1; i += 64) {
    float iv = inv[i];
    float w = iv * iv;
    int g = batch[i];
    uint4 v = *(const uint4*)(h2 + (size_t)i * HH + cbase);
    float* qr = &qlds[g * 32 + ln * 8];
    atomicAdd(&qr[0], w * b2f(v.x & 0xFFFFu));
    atomicAdd(&qr[1], w * b2f(v.x >> 16));
    atomicAdd(&qr[2], w * b2f(v.y & 0xFFFFu));
    atomicAdd(&qr[3], w * b2f(v.y >> 16));
    atomicAdd(&qr[4], w * b2f(v.z & 0xFFFFu));
    atomicAdd(&qr[5], w * b2f(v.z >> 16));
    atomicAdd(&qr[6], w * b2f(v.w & 0xFFFFu));
    atomicAdd(&qr[7], w * b2f(v.w >> 16));
    if (do_s) atomicAdd(&slds[g], w);
  }
  __syncthreads();

  // drain
  for (int k = tid; k < NG * 32; k += 256) {
    float v = qlds[k];
    if (v != 0.f) atomicAdd(&q[(k >> 5) * HH + y * 32 + (k & 31)], v);
  }
  if (y == 0 && tid < NG) {
    float v = slds[tid];
    if (v != 0.f) atomicAdd(&S[tid], v);
  }
}

// ================= decoder (pooled = q @ Wc + S*bc, then 2-layer MLP) =================
__global__ void k_dec(const float* __restrict__ q, const float* __restrict__ S,
                      const float* __restrict__ Wc, const float* __restrict__ bc,
                      const float* __restrict__ w1, const float* __restrict__ b1,
                      const float* __restrict__ w2, const float* __restrict__ b2,
                      float* __restrict__ out) {
  __shared__ float qs[128], p[128], t[128];
  int g = blockIdx.x, j = threadIdx.x;
  qs[j] = q[g * HH + j];
  __syncthreads();
  float sg = S[g];
  float a = sg * bc[j];
  for (int k = 0; k < 128; ++k) a += qs[k] * Wc[k * 128 + j];
  p[j] = a;
  __syncthreads();
  a = b1[j];
  for (int k = 0; k < 128; ++k) a += p[k] * w1[k * 128 + j];
  t[j] = fmaxf(a, 0.f);
  __syncthreads();
  if (j < 10) {
    float o = b2[j];
    for (int k = 0; k < 128; ++k) o += t[k] * w2[k * 10 + j];
    out[g * 10 + j] = o;
  }
}

extern "C" void kernel_launch(void* const* d_in, const int* in_sizes, int n_in,
                              void* d_out, int out_size, void* d_ws, size_t ws_size,
                              hipStream_t stream) {
  const float* x       = (const float*)d_in[0];
  const int*   eidx    = (const int*)d_in[1];
  const int*   src     = eidx;            // edge_index[0]
  const int*   dst     = eidx + NE;       // edge_index[1]
  const int*   batch   = (const int*)d_in[3];
  const float* enc_w1  = (const float*)d_in[4];
  const float* enc_b1  = (const float*)d_in[5];
  const float* enc_w2  = (const float*)d_in[6];
  const float* enc_b2  = (const float*)d_in[7];
  const float* conv_w  = (const float*)d_in[8];
  const float* conv_b  = (const float*)d_in[9];
  const float* dec_w1  = (const float*)d_in[10];
  const float* dec_b1  = (const float*)d_in[11];
  const float* dec_w2  = (const float*)d_in[12];
  const float* dec_b2  = (const float*)d_in[13];
  float* out = (float*)d_out;

  char* ws = (char*)d_ws;
  size_t o = 0;
  auto alloc = [&](size_t bytes) -> char* {
    char* p = ws + o;
    o += (bytes + 255) & ~(size_t)255;
    return p;
  };
  int*      off     = (int*)alloc((size_t)(NN + 1) * 4);
  int*      csrs    = (int*)alloc((size_t)NE * 4);
  float*    inv     = (float*)alloc((size_t)NN * 4);
  int*      blkcntA = (int*)alloc((size_t)NBLK * NB * 4);
  int*      poffA   = (int*)alloc((size_t)NBLK * NB * 4);
  int*      blkcntB = (int*)alloc((size_t)NBLK * NB * 4);
  int*      poffB   = (int*)alloc((size_t)NBLK * NB * 4);
  int*      colsumA = (int*)alloc((size_t)NB * 4);
  int*      colsumB = (int*)alloc((size_t)NB * 4);
  int*      gbaseA  = (int*)alloc((size_t)(NB + 1) * 4);
  int*      gbaseB  = (int*)alloc((size_t)(NB + 1) * 4);
  int*      dhist   = (int*)alloc(64 * 4);
  int*      dcur    = (int*)alloc(64 * 4);
  int*      order   = (int*)alloc((size_t)NN * 4);
  float*    q       = (float*)alloc((size_t)NG * HH * 4);
  float*    Sg      = (float*)alloc((size_t)NG * 4);
  uint2*    pairsA  = (uint2*)alloc((size_t)NE * 8);       // dedicated: survives until prep
  uint32_t* esg     = (uint32_t*)alloc((size_t)NE * 4);
  float*    ew      = (float*)alloc((size_t)NE * 4);
  uint16_t* buf0    = (uint16_t*)alloc((size_t)NN * HH * 2);
  uint16_t* buf1    = (uint16_t*)alloc((size_t)NN * HH * 2);
  uint32_t* pairB   = (uint32_t*)buf1;    // alias: dead before encoder

  hipMemsetAsync(dhist, 0, 64 * 4, stream);
  hipMemsetAsync(q, 0, (size_t)NG * HH * 4, stream);
  hipMemsetAsync(Sg, 0, (size_t)NG * 4, stream);

  // CSR build: sort by src-bucket, then stable by dst-bucket, then per-bucket by dst node
  k_cntA<<<dim3(NBLK), dim3(256), 0, stream>>>(src, blkcntA);
  k_colscan<<<dim3(NB), dim3(64), 0, stream>>>(blkcntA, poffA, colsumA);
  k_gscan<<<dim3(1), dim3(256), 0, stream>>>(colsumA, gbaseA, off, 0);
  k_placeA<<<dim3(NBLK), dim3(256), 0, stream>>>(src, dst, poffA, gbaseA, pairsA);
  k_cntB<<<dim3(NBLK), dim3(256), 0, stream>>>(pairsA, blkcntB);
  k_colscan<<<dim3(NB), dim3(64), 0, stream>>>(blkcntB, poffB, colsumB);
  k_gscan<<<dim3(1), dim3(256), 0, stream>>>(colsumB, gbaseB, off, 1);
  k_placeB<<<dim3(NBLK), dim3(256), 0, stream>>>(pairsA, poffB, gbaseB, pairB);
  k_bucket_sort<<<dim3(NB), dim3(256), 0, stream>>>(pairB, gbaseB, off, inv, csrs);

  // degree hist + LPT order
  const int NBK = (NN + 255) / 256;
  k_deghist<<<dim3(NBK), dim3(256), 0, stream>>>(off, dhist);
  k_dscan<<<dim3(1), dim3(64), 0, stream>>>(dhist, dcur);
  k_dplace<<<dim3(NBK), dim3(256), 0, stream>>>(off, dcur, order);

  // fused-last-layer edge prep (needs inv; pairsA still valid)
  k_prep_edges<<<dim3((NE + 255) / 256), dim3(256), 0, stream>>>(pairsA, inv, batch, esg, ew);

  // encoder (first GEMM reads fp32 x directly)
  const int GB = (NN + 127) / 128;   // 782
  k_gemm<<<dim3(GB), dim3(256), 0, stream>>>(nullptr, x, enc_w1, enc_b1, nullptr, buf1, NN, 1);
  k_gemm<<<dim3(GB), dim3(256), 0, stream>>>(buf1, nullptr, enc_w2, enc_b2, nullptr, buf0, NN, 0);

  // GCN layers 0,1: conv GEMM (inv-prescaled) + gather-sum agg
  const int AB = (NN + 15) / 16;   // 6250
  k_gemm<<<dim3(GB), dim3(256), 0, stream>>>(buf0, nullptr, conv_w + 0 * 16384, conv_b + 0,   inv, buf1, NN, 0);
  k_agg <<<dim3(AB), dim3(256), 0, stream>>>(buf1, off, csrs, inv, order, buf0, 1);
  k_gemm<<<dim3(GB), dim3(256), 0, stream>>>(buf0, nullptr, conv_w + 1 * 16384, conv_b + 128, inv, buf1, NN, 0);
  k_agg <<<dim3(AB), dim3(256), 0, stream>>>(buf1, off, csrs, inv, order, buf0, 1);

  // GCN layer 2 + pool fused: linear, src-major streaming
  k_edgepool<<<dim3(98, 4), dim3(256), 0, stream>>>(buf0, esg, ew, inv, batch, q, Sg);

  // decoder (folds conv W2/b2)
  k_dec<<<dim3(NG), dim3(128), 0, stream>>>(q, Sg, conv_w + 2 * 16384, conv_b + 256,
                                            dec_w1, dec_b1, dec_w2, dec_b2, out);
}

// Round 9
// 523.923 us; speedup vs baseline: 3.6057x; 3.6057x over previous
//
#include <hip/hip_runtime.h>
#include <hip/hip_bf16.h>
#include <cstdint>
#include <cstddef>

#define NN 100000      // nodes
#define NE 1600000     // edges
#define HH 128         // hidden dim
#define NG 256         // graphs

#define NB 196         // buckets (512 nodes each; 196*512 = 100352 >= NN)
#define BSH 9          // bucket shift
#define BMSK 511
#define CHUNK 16384    // edges per binning block
#define NBLK 98        // ceil(NE / CHUNK)

typedef __bf16 bf16x8 __attribute__((ext_vector_type(8)));
typedef float floatx4 __attribute__((ext_vector_type(4)));

__device__ __forceinline__ uint32_t f2b(float f) {
  union { float f; uint32_t u; } v; v.f = f;
  uint32_t u = v.u;
  return (u + 0x7FFFu + ((u >> 16) & 1u)) >> 16;   // RNE to bf16 (raw 16 bits)
}
__device__ __forceinline__ float b2f(uint32_t h) {
  union { uint32_t u; float f; } v; v.u = h << 16;
  return v.f;
}
__device__ __forceinline__ void addrow(float* a, uint4 v) {
  a[0] += b2f(v.x & 0xFFFFu); a[1] += b2f(v.x >> 16);
  a[2] += b2f(v.y & 0xFFFFu); a[3] += b2f(v.y >> 16);
  a[4] += b2f(v.z & 0xFFFFu); a[5] += b2f(v.z >> 16);
  a[6] += b2f(v.w & 0xFFFFu); a[7] += b2f(v.w >> 16);
}

// ================= CSR build: src-bucket sort, then dst-bucket counting sort =================

__global__ __launch_bounds__(256) void k_cntA(const int* __restrict__ src,
                                              int* __restrict__ blkcnt) {
  __shared__ int h[NB];
  int t = threadIdx.x;
  if (t < NB) h[t] = 0;
  __syncthreads();
  int base = blockIdx.x * CHUNK, end = min(base + CHUNK, NE);
  for (int i = base + t; i < end; i += 256) atomicAdd(&h[src[i] >> BSH], 1);
  __syncthreads();
  if (t < NB) blkcnt[blockIdx.x * NB + t] = h[t];
}

__global__ __launch_bounds__(256) void k_cntB(const uint2* __restrict__ pairs,
                                              int* __restrict__ blkcnt) {
  __shared__ int h[NB];
  int t = threadIdx.x;
  if (t < NB) h[t] = 0;
  __syncthreads();
  int base = blockIdx.x * CHUNK, end = min(base + CHUNK, NE);
  for (int i = base + t; i < end; i += 256) atomicAdd(&h[pairs[i].y >> BSH], 1);
  __syncthreads();
  if (t < NB) blkcnt[blockIdx.x * NB + t] = h[t];
}

__global__ __launch_bounds__(64) void k_colscan(const int* __restrict__ blkcnt,
                                                int* __restrict__ poff,
                                                int* __restrict__ colsum) {
  int b = blockIdx.x, t = threadIdx.x;
  int carry = 0;
  for (int base = 0; base < NBLK; base += 64) {
    int r = base + t;
    int x = (r < NBLK) ? blkcnt[r * NB + b] : 0;
    int v = x;
    for (int d = 1; d < 64; d <<= 1) { int u = __shfl_up(v, d); if (t >= d) v += u; }
    if (r < NBLK) poff[r * NB + b] = carry + v - x;
    carry += __shfl(v, 63);
  }
  if (t == 0) colsum[b] = carry;
}

__global__ void k_gscan(const int* __restrict__ colsum, int* __restrict__ gbase,
                        int* __restrict__ off, int set_off) {
  __shared__ int s[256];
  int t = threadIdx.x;
  int x = (t < NB) ? colsum[t] : 0;
  s[t] = x; __syncthreads();
  for (int d = 1; d < 256; d <<= 1) {
    int v = (t >= d) ? s[t - d] : 0;
    __syncthreads();
    s[t] += v;
    __syncthreads();
  }
  if (t < NB) gbase[t] = s[t] - x;
  if (t == 0) { gbase[NB] = NE; if (set_off) off[NN] = NE; }
}

__global__ __launch_bounds__(256) void k_placeA(const int* __restrict__ src,
                                                const int* __restrict__ dst,
                                                const int* __restrict__ poff,
                                                const int* __restrict__ gbase,
                                                uint2* __restrict__ pairs) {
  __shared__ int cur[NB];
  int t = threadIdx.x;
  if (t < NB) cur[t] = poff[blockIdx.x * NB + t] + gbase[t];
  __syncthreads();
  int base = blockIdx.x * CHUNK, end = min(base + CHUNK, NE);
  for (int i = base + t; i < end; i += 256) {
    int s = src[i], d = dst[i];
    int p = atomicAdd(&cur[s >> BSH], 1);
    pairs[p] = make_uint2((unsigned)s, (unsigned)d);
  }
}

__global__ __launch_bounds__(256) void k_placeB(const uint2* __restrict__ pairs,
                                                const int* __restrict__ poff,
                                                const int* __restrict__ gbase,
                                                uint32_t* __restrict__ outb) {
  __shared__ int cur[NB];
  int t = threadIdx.x;
  if (t < NB) cur[t] = poff[blockIdx.x * NB + t] + gbase[t];
  __syncthreads();
  int base = blockIdx.x * CHUNK, end = min(base + CHUNK, NE);
  for (int i = base + t; i < end; i += 256) {
    uint2 v = pairs[i];
    int p = atomicAdd(&cur[v.y >> BSH], 1);
    outb[p] = v.x | ((v.y & (unsigned)BMSK) << 17);
  }
}

__global__ __launch_bounds__(256) void k_bucket_sort(
    const uint32_t* __restrict__ pairbuf, const int* __restrict__ gbase,
    int* __restrict__ off, float* __restrict__ inv, int* __restrict__ csrs)
{
  __shared__ int cnt[512];
  __shared__ int loff[512];
  __shared__ int psum[256];
  int b = blockIdx.x;
  int tid = threadIdx.x;
  cnt[tid] = 0; cnt[tid + 256] = 0;
  __syncthreads();
  int s0 = gbase[b], s1 = gbase[b + 1];
  for (int i = s0 + tid; i < s1; i += 256)
    atomicAdd(&cnt[pairbuf[i] >> 17], 1);
  __syncthreads();
  int a0 = cnt[2 * tid], a1 = cnt[2 * tid + 1];
  int s = a0 + a1;
  psum[tid] = s;
  __syncthreads();
  for (int d = 1; d < 256; d <<= 1) {
    int v = (tid >= d) ? psum[tid - d] : 0;
    __syncthreads();
    psum[tid] += v;
    __syncthreads();
  }
  int excl = psum[tid] - s;
  loff[2 * tid] = excl;
  loff[2 * tid + 1] = excl + a0;
  __syncthreads();
#pragma unroll
  for (int k = 0; k < 2; ++k) {
    int i = tid + k * 256;
    int node = b * 512 + i;
    if (node < NN) {
      off[node] = s0 + loff[i];
      inv[node] = rsqrtf((float)cnt[i] + 1.0f);
    }
  }
  __syncthreads();
  cnt[tid] = loff[tid]; cnt[tid + 256] = loff[tid + 256];
  __syncthreads();
  for (int i = s0 + tid; i < s1; i += 256) {
    uint32_t v = pairbuf[i];
    int p = atomicAdd(&cnt[v >> 17], 1);
    csrs[s0 + p] = (int)(v & 0x1FFFFu);
  }
}

// ================= node prep: degree hist + graph boundaries (merged) =================
__global__ __launch_bounds__(256) void k_nodeprep(const int* __restrict__ off,
                                                  const int* __restrict__ batch,
                                                  int* __restrict__ dhist,
                                                  int* __restrict__ gstart) {
  __shared__ int h[64];
  int t = threadIdx.x;
  if (t < 64) h[t] = 0;
  __syncthreads();
  int i = blockIdx.x * 256 + t;
  if (i < NN) {
    int d = off[i + 1] - off[i]; if (d > 63) d = 63;
    atomicAdd(&h[d], 1);
    int b = batch[i];
    if (i == 0) {
      for (int g = 0; g <= b; ++g) gstart[g] = 0;
    } else {
      int a = batch[i - 1];
      for (int g = a + 1; g <= b; ++g) gstart[g] = i;
    }
    if (i == NN - 1) {
      for (int g = b + 1; g <= NG; ++g) gstart[g] = NN;
    }
  }
  __syncthreads();
  if (t < 64 && h[t]) atomicAdd(&dhist[t], h[t]);
}

__global__ void k_dscan(const int* __restrict__ dhist, int* __restrict__ dcur) {
  int t = threadIdx.x;             // 64 threads; descending order (LPT)
  int x = dhist[63 - t];
  int v = x;
  for (int d = 1; d < 64; d <<= 1) { int u = __shfl_up(v, d); if (t >= d) v += u; }
  dcur[63 - t] = v - x;
}

__global__ __launch_bounds__(256) void k_dplace(const int* __restrict__ off,
                                                int* __restrict__ dcur,
                                                int* __restrict__ order) {
  __shared__ int h[64], base[64];
  int t = threadIdx.x;
  if (t < 64) h[t] = 0;
  __syncthreads();
  int i = blockIdx.x * 256 + t;
  int d = 0, ld = 0;
  if (i < NN) { d = off[i + 1] - off[i]; if (d > 63) d = 63; ld = atomicAdd(&h[d], 1); }
  __syncthreads();
  if (t < 64) base[t] = h[t] ? atomicAdd(&dcur[t], h[t]) : 0;
  __syncthreads();
  if (i < NN) order[base[d] + ld] = i;
}

// ================= GEMM: Out[M,128] = bf16( scale[r] * (relu?(A@W + bias)) ) =================
__global__ __launch_bounds__(256) void k_gemm(
    const uint16_t* __restrict__ A16, const float* __restrict__ A32,
    const float* __restrict__ W, const float* __restrict__ bias,
    const float* __restrict__ scale,      // nullptr or per-row scale (inv)
    uint16_t* __restrict__ Out, int M, int do_relu)
{
  __shared__ uint16_t Wt[128][136];
  const int tid = threadIdx.x;

  for (int it = 0; it < 16; ++it) {
    int idx = tid + it * 256;
    int n = idx & 127;
    int k0 = (idx >> 7) * 4;
    uint2 wv;
    wv.x = f2b(W[(k0 + 0) * 128 + n]) | (f2b(W[(k0 + 1) * 128 + n]) << 16);
    wv.y = f2b(W[(k0 + 2) * 128 + n]) | (f2b(W[(k0 + 3) * 128 + n]) << 16);
    *(uint2*)&Wt[n][k0] = wv;
  }
  __syncthreads();

  const int lane = tid & 63;
  const int wave = tid >> 6;
  const int lrow = lane & 15;
  const int lk = (lane >> 4) * 8;
  const int row0 = blockIdx.x * 128 + wave * 32;

  floatx4 acc[2][8];
#pragma unroll
  for (int t = 0; t < 2; ++t)
#pragma unroll
    for (int n = 0; n < 8; ++n)
      acc[t][n] = (floatx4){0.f, 0.f, 0.f, 0.f};

#pragma unroll
  for (int ks = 0; ks < 4; ++ks) {
    bf16x8 a[2];
#pragma unroll
    for (int t = 0; t < 2; ++t) {
      int r = row0 + t * 16 + lrow;
      uint4 tmp = {0u, 0u, 0u, 0u};
      if (r < M) {
        if (A32) {
          float4 f0 = *(const float4*)(A32 + (size_t)r * HH + ks * 32 + lk);
          float4 f1 = *(const float4*)(A32 + (size_t)r * HH + ks * 32 + lk + 4);
          tmp.x = f2b(f0.x) | (f2b(f0.y) << 16);
          tmp.y = f2b(f0.z) | (f2b(f0.w) << 16);
          tmp.z = f2b(f1.x) | (f2b(f1.y) << 16);
          tmp.w = f2b(f1.z) | (f2b(f1.w) << 16);
        } else {
          tmp = *(const uint4*)(A16 + (size_t)r * HH + ks * 32 + lk);
        }
      }
      a[t] = __builtin_bit_cast(bf16x8, tmp);
    }
#pragma unroll
    for (int n = 0; n < 8; ++n) {
      bf16x8 b = __builtin_bit_cast(bf16x8, *(const uint4*)&Wt[n * 16 + lrow][ks * 32 + lk]);
      acc[0][n] = __builtin_amdgcn_mfma_f32_16x16x32_bf16(a[0], b, acc[0][n], 0, 0, 0);
      acc[1][n] = __builtin_amdgcn_mfma_f32_16x16x32_bf16(a[1], b, acc[1][n], 0, 0, 0);
    }
  }

  float bc[8];
#pragma unroll
  for (int n = 0; n < 8; ++n) bc[n] = bias[n * 16 + lrow];

  const int rbase = (lane >> 4) * 4;
#pragma unroll
  for (int t = 0; t < 2; ++t) {
#pragma unroll
    for (int r = 0; r < 4; ++r) {
      int row = row0 + t * 16 + rbase + r;
      if (row < M) {
        float sc = scale ? scale[row] : 1.0f;
#pragma unroll
        for (int n = 0; n < 8; ++n) {
          float v = acc[t][n][r] + bc[n];
          if (do_relu) v = fmaxf(v, 0.f);
          v *= sc;
          Out[(size_t)row * HH + n * 16 + lrow] = (uint16_t)f2b(v);
        }
      }
    }
  }
}

// ================= aggregation: pre-scaled rows, pure gather-sum, unroll-4 =================
__global__ __launch_bounds__(256) void k_agg(
    const uint16_t* __restrict__ hw2, const int* __restrict__ off,
    const int* __restrict__ csrs, const float* __restrict__ inv,
    const int* __restrict__ order,
    uint16_t* __restrict__ hout, int do_relu)
{
  int slot = blockIdx.x * 16 + (threadIdx.x >> 4);
  if (slot >= NN) return;
  int node = order[slot];
  int c = (threadIdx.x & 15) * 8;   // 8 channels = 16 B per lane

  uint4 sv = *(const uint4*)(hw2 + (size_t)node * HH + c);
  float a[8] = {0.f, 0.f, 0.f, 0.f, 0.f, 0.f, 0.f, 0.f};
  addrow(a, sv);                    // self term (already inv[node]-scaled)

  int e0 = off[node], e1 = off[node + 1];
  int e = e0;
  for (; e + 4 <= e1; e += 4) {
    int s0 = csrs[e + 0], s1 = csrs[e + 1], s2 = csrs[e + 2], s3 = csrs[e + 3];
    uint4 v0 = *(const uint4*)(hw2 + (size_t)s0 * HH + c);
    uint4 v1 = *(const uint4*)(hw2 + (size_t)s1 * HH + c);
    uint4 v2 = *(const uint4*)(hw2 + (size_t)s2 * HH + c);
    uint4 v3 = *(const uint4*)(hw2 + (size_t)s3 * HH + c);
    addrow(a, v0); addrow(a, v1); addrow(a, v2); addrow(a, v3);
  }
  for (; e < e1; ++e) {
    int s = csrs[e];
    uint4 v = *(const uint4*)(hw2 + (size_t)s * HH + c);
    addrow(a, v);
  }
  float invd = inv[node];
#pragma unroll
  for (int j = 0; j < 8; ++j) {
    a[j] *= invd;
    if (do_relu) a[j] = fmaxf(a[j], 0.f);
  }
  uint4 o;
  o.x = f2b(a[0]) | (f2b(a[1]) << 16);
  o.y = f2b(a[2]) | (f2b(a[3]) << 16);
  o.z = f2b(a[4]) | (f2b(a[5]) << 16);
  o.w = f2b(a[6]) | (f2b(a[7]) << 16);
  *(uint4*)(hout + (size_t)node * HH + c) = o;
}

// ================= global add pool: one block per graph, zero atomics =================
__global__ __launch_bounds__(256) void k_pool(const uint16_t* __restrict__ h,
                                              const int* __restrict__ gstart,
                                              float* __restrict__ pooled) {
  __shared__ float red[16][132];   // +4 pad
  int g = blockIdx.x;
  int tid = threadIdx.x;
  int slot = tid >> 4;
  int c = (tid & 15) * 8;

  int r0 = gstart[g], r1 = gstart[g + 1];
  float a[8] = {0.f, 0.f, 0.f, 0.f, 0.f, 0.f, 0.f, 0.f};
  for (int r = r0 + slot; r < r1; r += 16) {
    uint4 v = *(const uint4*)(h + (size_t)r * HH + c);
    a[0] += b2f(v.x & 0xFFFFu); a[1] += b2f(v.x >> 16);
    a[2] += b2f(v.y & 0xFFFFu); a[3] += b2f(v.y >> 16);
    a[4] += b2f(v.z & 0xFFFFu); a[5] += b2f(v.z >> 16);
    a[6] += b2f(v.w & 0xFFFFu); a[7] += b2f(v.w >> 16);
  }
  *(float4*)&red[slot][c]     = make_float4(a[0], a[1], a[2], a[3]);
  *(float4*)&red[slot][c + 4] = make_float4(a[4], a[5], a[6], a[7]);
  __syncthreads();
  if (tid < 128) {
    float s = 0.f;
#pragma unroll
    for (int k = 0; k < 16; ++k) s += red[k][tid];
    pooled[g * HH + tid] = s;
  }
}

// ================= decoder =================
__global__ void k_dec(const float* __restrict__ pooled,
                      const float* __restrict__ w1, const float* __restrict__ b1,
                      const float* __restrict__ w2, const float* __restrict__ b2,
                      float* __restrict__ out) {
  __shared__ float p[128], t[128];
  int g = blockIdx.x, j = threadIdx.x;
  p[j] = pooled[g * HH + j];
  __syncthreads();
  float a = b1[j];
  for (int k = 0; k < 128; ++k) a += p[k] * w1[k * 128 + j];
  t[j] = fmaxf(a, 0.f);
  __syncthreads();
  if (j < 10) {
    float o = b2[j];
    for (int k = 0; k < 128; ++k) o += t[k] * w2[k * 10 + j];
    out[g * 10 + j] = o;
  }
}

extern "C" void kernel_launch(void* const* d_in, const int* in_sizes, int n_in,
                              void* d_out, int out_size, void* d_ws, size_t ws_size,
                              hipStream_t stream) {
  const float* x       = (const float*)d_in[0];
  const int*   eidx    = (const int*)d_in[1];
  const int*   src     = eidx;            // edge_index[0]
  const int*   dst     = eidx + NE;       // edge_index[1]
  const int*   batch   = (const int*)d_in[3];
  const float* enc_w1  = (const float*)d_in[4];
  const float* enc_b1  = (const float*)d_in[5];
  const float* enc_w2  = (const float*)d_in[6];
  const float* enc_b2  = (const float*)d_in[7];
  const float* conv_w  = (const float*)d_in[8];
  const float* conv_b  = (const float*)d_in[9];
  const float* dec_w1  = (const float*)d_in[10];
  const float* dec_b1  = (const float*)d_in[11];
  const float* dec_w2  = (const float*)d_in[12];
  const float* dec_b2  = (const float*)d_in[13];
  float* out = (float*)d_out;

  char* ws = (char*)d_ws;
  size_t o = 0;
  auto alloc = [&](size_t bytes) -> char* {
    char* p = ws + o;
    o += (bytes + 255) & ~(size_t)255;
    return p;
  };
  int*      off     = (int*)alloc((size_t)(NN + 1) * 4);
  int*      csrs    = (int*)alloc((size_t)NE * 4);
  float*    inv     = (float*)alloc((size_t)NN * 4);
  float*    pooled  = (float*)alloc((size_t)NG * HH * 4);
  int*      blkcntA = (int*)alloc((size_t)NBLK * NB * 4);
  int*      poffA   = (int*)alloc((size_t)NBLK * NB * 4);
  int*      blkcntB = (int*)alloc((size_t)NBLK * NB * 4);
  int*      poffB   = (int*)alloc((size_t)NBLK * NB * 4);
  int*      colsumA = (int*)alloc((size_t)NB * 4);
  int*      colsumB = (int*)alloc((size_t)NB * 4);
  int*      gbaseA  = (int*)alloc((size_t)(NB + 1) * 4);
  int*      gbaseB  = (int*)alloc((size_t)(NB + 1) * 4);
  int*      dhist   = (int*)alloc(64 * 4);
  int*      dcur    = (int*)alloc(64 * 4);
  int*      order   = (int*)alloc((size_t)NN * 4);
  int*      gstart  = (int*)alloc((size_t)(NG + 1) * 4);
  uint16_t* buf0    = (uint16_t*)alloc((size_t)NN * HH * 2);
  uint16_t* buf1    = (uint16_t*)alloc((size_t)NN * HH * 2);
  uint2*    pairsA  = (uint2*)buf1;                          // 12.8 MB, dead before encoder
  uint32_t* pairB   = (uint32_t*)((char*)buf1 + (size_t)NE * 8);  // +6.4 MB, still < 25.6 MB

  hipMemsetAsync(dhist, 0, 64 * 4, stream);

  // CSR build: sort by src-bucket, then stable by dst-bucket, then per-bucket by dst node
  k_cntA<<<dim3(NBLK), dim3(256), 0, stream>>>(src, blkcntA);
  k_colscan<<<dim3(NB), dim3(64), 0, stream>>>(blkcntA, poffA, colsumA);
  k_gscan<<<dim3(1), dim3(256), 0, stream>>>(colsumA, gbaseA, off, 0);
  k_placeA<<<dim3(NBLK), dim3(256), 0, stream>>>(src, dst, poffA, gbaseA, pairsA);
  k_cntB<<<dim3(NBLK), dim3(256), 0, stream>>>(pairsA, blkcntB);
  k_colscan<<<dim3(NB), dim3(64), 0, stream>>>(blkcntB, poffB, colsumB);
  k_gscan<<<dim3(1), dim3(256), 0, stream>>>(colsumB, gbaseB, off, 1);
  k_placeB<<<dim3(NBLK), dim3(256), 0, stream>>>(pairsA, poffB, gbaseB, pairB);
  k_bucket_sort<<<dim3(NB), dim3(256), 0, stream>>>(pairB, gbaseB, off, inv, csrs);

  // degree hist + graph bounds (merged), then LPT order
  const int NBK = (NN + 255) / 256;
  k_nodeprep<<<dim3(NBK), dim3(256), 0, stream>>>(off, batch, dhist, gstart);
  k_dscan<<<dim3(1), dim3(64), 0, stream>>>(dhist, dcur);
  k_dplace<<<dim3(NBK), dim3(256), 0, stream>>>(off, dcur, order);

  // encoder (first GEMM reads fp32 x directly)
  const int GB = (NN + 127) / 128;   // 782
  k_gemm<<<dim3(GB), dim3(256), 0, stream>>>(nullptr, x, enc_w1, enc_b1, nullptr, buf1, NN, 1);
  k_gemm<<<dim3(GB), dim3(256), 0, stream>>>(buf1, nullptr, enc_w2, enc_b2, nullptr, buf0, NN, 0);

  // 3 GCN layers: conv GEMM writes inv[r]-pre-scaled rows; agg is pure gather-sum
  const int AB = (NN + 15) / 16;   // 6250
  k_gemm<<<dim3(GB), dim3(256), 0, stream>>>(buf0, nullptr, conv_w + 0 * 16384, conv_b + 0,   inv, buf1, NN, 0);
  k_agg <<<dim3(AB), dim3(256), 0, stream>>>(buf1, off, csrs, inv, order, buf0, 1);
  k_gemm<<<dim3(GB), dim3(256), 0, stream>>>(buf0, nullptr, conv_w + 1 * 16384, conv_b + 128, inv, buf1, NN, 0);
  k_agg <<<dim3(AB), dim3(256), 0, stream>>>(buf1, off, csrs, inv, order, buf0, 1);
  k_gemm<<<dim3(GB), dim3(256), 0, stream>>>(buf0, nullptr, conv_w + 2 * 16384, conv_b + 256, inv, buf1, NN, 0);
  k_agg <<<dim3(AB), dim3(256), 0, stream>>>(buf1, off, csrs, inv, order, buf0, 0);

  // pool + decoder
  k_pool<<<dim3(NG), dim3(256), 0, stream>>>(buf0, gstart, pooled);
  k_dec<<<dim3(NG), dim3(128), 0, stream>>>(pooled, dec_w1, dec_b1, dec_w2, dec_b2, out);
}